// Round 6
// baseline (256.061 us; speedup 1.0000x reference)
//
#include <hip/hip_runtime.h>
#include <hip/hip_bf16.h>

#define B_ 4
#define T_ 2048
#define C_ 1024
#define H_ 16
#define D_ 64

typedef __attribute__((ext_vector_type(8))) short short8;
typedef __attribute__((ext_vector_type(4))) float f32x4;

// q pre-scale: (1/sqrt(D)) * log2(e) so attn uses raw v_exp_f32 (exp2)
#define QSCALE 0.18033688011112042f

static __device__ __forceinline__ unsigned short f2bf(float f) {
  unsigned u = __float_as_uint(f);
  u += 0x7fff + ((u >> 16) & 1);  // round-to-nearest-even
  return (unsigned short)(u >> 16);
}

// packed bf16 convert: dword = {bf16(lo), bf16(hi)<<16}, RNE (T12 primitive)
static __device__ __forceinline__ unsigned cvt_pk_bf16(float lo, float hi) {
  unsigned r;
  asm("v_cvt_pk_bf16_f32 %0, %1, %2" : "=v"(r) : "v"(lo), "v"(hi));
  return r;
}

static __device__ __forceinline__ float fast_exp2(float x) {
#if __has_builtin(__builtin_amdgcn_exp2f)
  return __builtin_amdgcn_exp2f(x);
#else
  return exp2f(x);
#endif
}

#define GL2LDS16(g, l)                                              \
  __builtin_amdgcn_global_load_lds(                                 \
      (const __attribute__((address_space(1))) void*)(g),           \
      (__attribute__((address_space(3))) void*)(l), 16, 0, 0)

// ---------------------------------------------------------------------------
// Fused pre-pass: x->bf16 (blocks 0..8191), Wqkv transpose (8192..11263),
// Wproj transpose (11264..12287).
// ---------------------------------------------------------------------------
__global__ __launch_bounds__(256) void prepass(
    const float* __restrict__ x, const float* __restrict__ Wq,
    const float* __restrict__ Wp, ushort* __restrict__ xb,
    ushort* __restrict__ Wqt, ushort* __restrict__ Wpt) {
  __shared__ ushort tile[32][33];
  const int bid = blockIdx.x;
  if (bid < 8192) {
    const size_t i = ((size_t)bid * 256 + threadIdx.x) * 4;
    float4 vv = *(const float4*)(x + i);
    ushort4 o = {f2bf(vv.x), f2bf(vv.y), f2bf(vv.z), f2bf(vv.w)};
    *(ushort4*)(xb + i) = o;
    return;
  }
  const float* in;
  ushort* out;
  int N, tix;
  if (bid < 8192 + 3072) {
    in = Wq; out = Wqt; N = 3 * C_; tix = bid - 8192;
  } else {
    in = Wp; out = Wpt; N = C_; tix = bid - 11264;
  }
  const int nT = N >> 5;
  const int k0 = (tix / nT) << 5, n0 = (tix % nT) << 5;
  const int r = threadIdx.x >> 3;
  const int c4 = (threadIdx.x & 7) << 2;
  float4 v = *(const float4*)(in + (size_t)(k0 + r) * N + n0 + c4);
  tile[c4 + 0][r] = f2bf(v.x);
  tile[c4 + 1][r] = f2bf(v.y);
  tile[c4 + 2][r] = f2bf(v.z);
  tile[c4 + 3][r] = f2bf(v.w);
  __syncthreads();
  ushort4 o = {tile[r][c4], tile[r][c4 + 1], tile[r][c4 + 2], tile[r][c4 + 3]};
  *(ushort4*)(out + (size_t)(n0 + r) * C_ + k0 + c4) = o;
}

// ---------------------------------------------------------------------------
// LDS XOR-swizzle fragment read for 128 B rows: chunk at position pos of row r
// holds global chunk pos ^ (r & 7). Staging pre-swizzles the SOURCE address.
// ---------------------------------------------------------------------------
static __device__ __forceinline__ int swz_frag64(int r, int quad, int ko) {
  return r * 128 + (((quad | (ko << 2)) ^ (r & 7)) << 4);  // bytes
}

// ---------------------------------------------------------------------------
// 8-phase-style GEMM template (both GEMMs): BM=128, BN=256, BK=64, 512 thr
// (8 waves, 2M x 4N, wave-tile 64x64). 3-slot LDS rotation (144 KB):
// iteration kt reads slot kt%3 (landed-proven), slot (kt+1)%3 is landing,
// stages for kt+2 issue into slot (kt+2)%3 (= slot freed at end of kt-1) --
// interleaved INTO the compute phases. Counted s_waitcnt vmcnt(6) once per
// K-tile (in-order vmem retirement => kt+1's 6 loads landed), raw s_barrier
// publishes. Never drains to 0 except the tail K-tile. Phases: ds-reads
// {af0+bf0, bf1, af1, -} (16 b128/K-tile, no refetch), 8 MFMA each with
// setprio(1), double-barrier phase lock (T3+T4+T5, per guide regime gate).
// ---------------------------------------------------------------------------
#define GEMM_MAINLOOP(A_, B_ptr, KA_, KB_)                                     \
  int aRow[2], aX[2], bRow[4], bX[4];                                          \
  _Pragma("unroll") for (int p = 0; p < 2; ++p) {                              \
    const int flat = p * 8192 + (int)threadIdx.x * 16;                         \
    aRow[p] = flat >> 7;                                                       \
    aX[p] = (((flat & 127) >> 4) ^ (aRow[p] & 7)) * 8;                         \
  }                                                                            \
  _Pragma("unroll") for (int p = 0; p < 4; ++p) {                              \
    const int flat = p * 8192 + (int)threadIdx.x * 16;                         \
    bRow[p] = flat >> 7;                                                       \
    bX[p] = (((flat & 127) >> 4) ^ (bRow[p] & 7)) * 8;                         \
  }                                                                            \
  int fOffA[2][4], fOffB[2][4];                                                \
  _Pragma("unroll") for (int ko = 0; ko < 2; ++ko) {                           \
    _Pragma("unroll") for (int i = 0; i < 4; ++i)                              \
        fOffA[ko][i] = swz_frag64(wm * 64 + i * 16 + c, quad, ko);             \
    _Pragma("unroll") for (int j = 0; j < 4; ++j)                              \
        fOffB[ko][j] = swz_frag64(wn * 64 + j * 16 + c, quad, ko);             \
  }                                                                            \
  _Pragma("unroll") for (int i = 0; i < 4; ++i)                                \
      _Pragma("unroll") for (int j = 0; j < 4; ++j) acc[i][j] =                \
          (f32x4){0.f, 0.f, 0.f, 0.f};                                         \
  /* prologue: stage kt=0 -> slot0, kt=1 -> slot1 (6 loads each) */            \
  _Pragma("unroll") for (int p = 0; p < 4; ++p)                                \
      GL2LDS16(B_ptr + (size_t)(n0 + bRow[p]) * C_ + bX[p],                    \
               (char*)KB_[0] + p * 8192 + wave * 1024);                        \
  _Pragma("unroll") for (int p = 0; p < 2; ++p)                                \
      GL2LDS16(A_ + (size_t)(m0 + aRow[p]) * C_ + aX[p],                       \
               (char*)KA_[0] + p * 8192 + wave * 1024);                        \
  _Pragma("unroll") for (int p = 0; p < 4; ++p)                                \
      GL2LDS16(B_ptr + (size_t)(n0 + bRow[p]) * C_ + 64 + bX[p],               \
               (char*)KB_[1] + p * 8192 + wave * 1024);                        \
  _Pragma("unroll") for (int p = 0; p < 2; ++p)                                \
      GL2LDS16(A_ + (size_t)(m0 + aRow[p]) * C_ + 64 + aX[p],                  \
               (char*)KA_[1] + p * 8192 + wave * 1024);                        \
  asm volatile("s_waitcnt vmcnt(6)" ::: "memory");                             \
  __builtin_amdgcn_s_barrier();                                                \
  int cur = 0, s2 = 2;                                                         \
  for (int kt = 0; kt < 16; ++kt) {                                            \
    const int kk2 = (kt + 2) << 6;                                             \
    const bool more = (kt + 2) < 16;                                           \
    const char* la = (const char*)KA_[cur];                                    \
    const char* lb = (const char*)KB_[cur];                                    \
    short8 af0[2][2], af1[2][2], bf0[2][2], bf1[2][2];                         \
    /* ---- phase 0: read af0 + bf0, stage B p0,p1; mfma i01 x j01 ---- */     \
    _Pragma("unroll") for (int d = 0; d < 2; ++d)                              \
        _Pragma("unroll") for (int ko = 0; ko < 2; ++ko) {                     \
      af0[d][ko] = *(const short8*)(la + fOffA[ko][d]);                        \
      bf0[d][ko] = *(const short8*)(lb + fOffB[ko][d]);                        \
    }                                                                          \
    if (more) {                                                                \
      GL2LDS16(B_ptr + (size_t)(n0 + bRow[0]) * C_ + kk2 + bX[0],              \
               (char*)KB_[s2] + 0 * 8192 + wave * 1024);                       \
      GL2LDS16(B_ptr + (size_t)(n0 + bRow[1]) * C_ + kk2 + bX[1],              \
               (char*)KB_[s2] + 1 * 8192 + wave * 1024);                       \
    }                                                                          \
    __builtin_amdgcn_s_barrier();                                              \
    __builtin_amdgcn_s_setprio(1);                                             \
    _Pragma("unroll") for (int di = 0; di < 2; ++di)                           \
        _Pragma("unroll") for (int dj = 0; dj < 2; ++dj)                       \
            _Pragma("unroll") for (int ko = 0; ko < 2; ++ko) acc[di][dj] =     \
                __builtin_amdgcn_mfma_f32_16x16x32_bf16(                       \
                    af0[di][ko], bf0[dj][ko], acc[di][dj], 0, 0, 0);           \
    __builtin_amdgcn_s_setprio(0);                                             \
    __builtin_amdgcn_s_barrier();                                              \
    /* ---- phase 1: read bf1, stage B p2,p3; mfma i01 x j23 ---- */           \
    _Pragma("unroll") for (int d = 0; d < 2; ++d)                              \
        _Pragma("unroll") for (int ko = 0; ko < 2; ++ko) bf1[d][ko] =          \
            *(const short8*)(lb + fOffB[ko][2 + d]);                           \
    if (more) {                                                                \
      GL2LDS16(B_ptr + (size_t)(n0 + bRow[2]) * C_ + kk2 + bX[2],              \
               (char*)KB_[s2] + 2 * 8192 + wave * 1024);                       \
      GL2LDS16(B_ptr + (size_t)(n0 + bRow[3]) * C_ + kk2 + bX[3],              \
               (char*)KB_[s2] + 3 * 8192 + wave * 1024);                       \
    }                                                                          \
    __builtin_amdgcn_s_barrier();                                              \
    __builtin_amdgcn_s_setprio(1);                                             \
    _Pragma("unroll") for (int di = 0; di < 2; ++di)                           \
        _Pragma("unroll") for (int dj = 0; dj < 2; ++dj)                       \
            _Pragma("unroll") for (int ko = 0; ko < 2; ++ko) acc[di][2 + dj] = \
                __builtin_amdgcn_mfma_f32_16x16x32_bf16(                       \
                    af0[di][ko], bf1[dj][ko], acc[di][2 + dj], 0, 0, 0);       \
    __builtin_amdgcn_s_setprio(0);                                             \
    __builtin_amdgcn_s_barrier();                                              \
    /* ---- phase 2: read af1, stage A p0; mfma i23 x j23 ---- */              \
    _Pragma("unroll") for (int d = 0; d < 2; ++d)                              \
        _Pragma("unroll") for (int ko = 0; ko < 2; ++ko) af1[d][ko] =          \
            *(const short8*)(la + fOffA[ko][2 + d]);                           \
    if (more)                                                                  \
      GL2LDS16(A_ + (size_t)(m0 + aRow[0]) * C_ + kk2 + aX[0],                 \
               (char*)KA_[s2] + 0 * 8192 + wave * 1024);                       \
    __builtin_amdgcn_s_barrier();                                              \
    __builtin_amdgcn_s_setprio(1);                                             \
    _Pragma("unroll") for (int di = 0; di < 2; ++di)                           \
        _Pragma("unroll") for (int dj = 0; dj < 2; ++dj)                       \
            _Pragma("unroll") for (int ko = 0; ko < 2; ++ko)                   \
                acc[2 + di][2 + dj] =                                          \
                    __builtin_amdgcn_mfma_f32_16x16x32_bf16(                   \
                        af1[di][ko], bf1[dj][ko], acc[2 + di][2 + dj], 0, 0,   \
                        0);                                                    \
    __builtin_amdgcn_s_setprio(0);                                             \
    __builtin_amdgcn_s_barrier();                                              \
    /* ---- phase 3: no reads, stage A p1; mfma i23 x j01 ---- */              \
    if (more)                                                                  \
      GL2LDS16(A_ + (size_t)(m0 + aRow[1]) * C_ + kk2 + aX[1],                 \
               (char*)KA_[s2] + 1 * 8192 + wave * 1024);                       \
    __builtin_amdgcn_s_barrier();                                              \
    __builtin_amdgcn_s_setprio(1);                                             \
    _Pragma("unroll") for (int di = 0; di < 2; ++di)                           \
        _Pragma("unroll") for (int dj = 0; dj < 2; ++dj)                       \
            _Pragma("unroll") for (int ko = 0; ko < 2; ++ko) acc[2 + di][dj] = \
                __builtin_amdgcn_mfma_f32_16x16x32_bf16(                       \
                    af1[di][ko], bf0[dj][ko], acc[2 + di][dj], 0, 0, 0);       \
    __builtin_amdgcn_s_setprio(0);                                             \
    __builtin_amdgcn_s_barrier();                                              \
    /* ---- end of K-tile: publish slot kt+1 ---- */                           \
    if (kt + 1 < 16) {                                                         \
      if (more)                                                                \
        asm volatile("s_waitcnt vmcnt(6)" ::: "memory");                       \
      else                                                                     \
        asm volatile("s_waitcnt vmcnt(0)" ::: "memory");                       \
      __builtin_amdgcn_s_barrier();                                            \
    }                                                                          \
    cur = (cur == 2) ? 0 : cur + 1;                                            \
    s2 = (s2 == 2) ? 0 : s2 + 1;                                               \
  }

// ---------------------------------------------------------------------------
// GEMM 1: qkv. q,k -> [B,H,T,D] bf16 (q pre-scaled); v -> [B,H,D,T].
// Grid 768 blocks (64 m-tiles x 12 n-tiles) = exactly 3 rounds at 1 blk/CU.
// ---------------------------------------------------------------------------
__global__ __launch_bounds__(512, 2) void gemm_qkv_mfma(
    const ushort* __restrict__ A, const ushort* __restrict__ Bt,
    const float* __restrict__ bias, ushort* __restrict__ q,
    ushort* __restrict__ k, ushort* __restrict__ v) {
  __shared__ __align__(16) ushort KA[3][128 * 64];
  __shared__ __align__(16) ushort KB[3][256 * 64];
  const int wave = threadIdx.x >> 6, lane = threadIdx.x & 63;
  const int c = lane & 15, quad = lane >> 4;
  const int wm = wave >> 2, wn = wave & 3;
  const int bid0 = blockIdx.x;
  const int bid = (bid0 & 7) * 96 + (bid0 >> 3);  // XCD chunking, bijective
  const int m0 = (bid / 12) << 7;
  const int n0 = (bid % 12) << 8;

  f32x4 acc[4][4];
  GEMM_MAINLOOP(A, Bt, KA, KB)

  const int s = n0 >> 10;  // uniform per block (256 | 1024)
  if (s == 2) {
    // v epilogue: [B,H,D,T], reg r spans 4 consecutive t -> ushort4
#pragma unroll
    for (int j = 0; j < 4; ++j) {
      const int n = n0 + wn * 64 + j * 16 + c;
      const int h = (n >> 6) & 15, d = n & 63;
      const float bval = bias[n];
#pragma unroll
      for (int i = 0; i < 4; ++i) {
        const int m = m0 + wm * 64 + i * 16 + quad * 4;
        const int b = m >> 11, t = m & 2047;
        ushort4 pk = {f2bf(acc[i][j][0] + bval), f2bf(acc[i][j][1] + bval),
                      f2bf(acc[i][j][2] + bval), f2bf(acc[i][j][3] + bval)};
        *(ushort4*)(v + (((size_t)((b << 4) + h) << 6) + d) * T_ + t) = pk;
      }
    }
  } else {
    ushort* outp = (s == 0) ? q : k;
    const float sc = (s == 0) ? QSCALE : 1.0f;
#pragma unroll
    for (int j = 0; j < 4; ++j) {
      const int n = n0 + wn * 64 + j * 16 + c;
      const int h = (n >> 6) & 15, d = n & 63;
      const float bval = bias[n];
#pragma unroll
      for (int i = 0; i < 4; ++i) {
#pragma unroll
        for (int r = 0; r < 4; ++r) {
          const int m = m0 + wm * 64 + i * 16 + quad * 4 + r;
          const int b = m >> 11, t = m & 2047;
          outp[(((size_t)((b << 4) + h) << 11) + t) * 64 + d] =
              f2bf((acc[i][j][r] + bval) * sc);
        }
      }
    }
  }
}

// ---------------------------------------------------------------------------
// GEMM 2: out = y2 @ Wproj + bproj (fp32 out). Grid 256 blocks
// (64 m-tiles x 4 n-tiles) = exactly 1 block per CU, single round.
// ---------------------------------------------------------------------------
__global__ __launch_bounds__(512, 2) void gemm_proj_mfma(
    const ushort* __restrict__ A, const ushort* __restrict__ Bt,
    const float* __restrict__ bias, float* __restrict__ out) {
  __shared__ __align__(16) ushort KA[3][128 * 64];
  __shared__ __align__(16) ushort KB[3][256 * 64];
  const int wave = threadIdx.x >> 6, lane = threadIdx.x & 63;
  const int c = lane & 15, quad = lane >> 4;
  const int wm = wave >> 2, wn = wave & 3;
  const int bid0 = blockIdx.x;
  const int bid = (bid0 & 7) * 32 + (bid0 >> 3);  // XCD chunking, bijective
  const int m0 = (bid >> 2) << 7;
  const int n0 = (bid & 3) << 8;

  f32x4 acc[4][4];
  GEMM_MAINLOOP(A, Bt, KA, KB)

#pragma unroll
  for (int j = 0; j < 4; ++j) {
    const int n = n0 + wn * 64 + j * 16 + c;
    const float bval = bias[n];
#pragma unroll
    for (int i = 0; i < 4; ++i) {
#pragma unroll
      for (int r = 0; r < 4; ++r) {
        const int m = m0 + wm * 64 + i * 16 + quad * 4 + r;
        out[(size_t)m * C_ + n] = acc[i][j][r] + bval;
      }
    }
  }
}

// ---------------------------------------------------------------------------
// Flash attention v8: async double-buffered K/V staging via global_load_lds
// (pre-swizzled source + swizzled frag reads), ONE barrier per KV-tile,
// stage-in-flight during compute. 3 blocks/CU + 256-block HW backfill queue.
// ---------------------------------------------------------------------------
__global__ __launch_bounds__(256) void attn(const ushort* __restrict__ q,
                                            const ushort* __restrict__ k,
                                            const ushort* __restrict__ v,
                                            ushort* __restrict__ y2) {
  const int qt = 15 - (int)(blockIdx.x >> 6);  // long tiles first
  const int bh = blockIdx.x & 63;
  const int t0 = qt << 7;
  const int w = threadIdx.x >> 6;
  const int lane = threadIdx.x & 63;
  const int c = lane & 15;
  const int quad = lane >> 4;

  const ushort* qp = q + (size_t)bh * T_ * D_;
  const ushort* kp = k + (size_t)bh * T_ * D_;
  const ushort* vp = v + (size_t)bh * D_ * T_;  // [d][t]

  __shared__ __align__(16) ushort Ks[2][64 * 64];  // [key][d], swizzled rows
  __shared__ __align__(16) ushort Vs[2][64 * 64];  // [d][key], swizzled rows
  __shared__ __align__(16) ushort Ps[4][32][72];   // per-wave [query][key]

  short8 qf[2][2];
#pragma unroll
  for (int g = 0; g < 2; ++g) {
    const ushort* qrow = qp + (size_t)(t0 + 32 * w + 16 * g + c) * D_;
    qf[g][0] = *(const short8*)(qrow + quad * 8);
    qf[g][1] = *(const short8*)(qrow + 32 + quad * 8);
  }

  int sRow[2], sX[2];
#pragma unroll
  for (int p = 0; p < 2; ++p) {
    const int flat = p * 4096 + (int)threadIdx.x * 16;
    sRow[p] = flat >> 7;
    sX[p] = (((flat & 127) >> 4) ^ (sRow[p] & 7)) * 8;  // ushort offset
  }

#define STAGE(buf, s0s)                                                   \
  do {                                                                    \
    _Pragma("unroll") for (int p = 0; p < 2; ++p) {                       \
      GL2LDS16(kp + (size_t)((s0s) + sRow[p]) * D_ + sX[p],               \
               (char*)Ks[buf] + p * 4096 + w * 1024);                     \
      GL2LDS16(vp + (size_t)sRow[p] * T_ + (s0s) + sX[p],                 \
               (char*)Vs[buf] + p * 4096 + w * 1024);                     \
    }                                                                     \
  } while (0)

  f32x4 o[2][4];
  float l_i[2] = {0.f, 0.f};
#pragma unroll
  for (int g = 0; g < 2; ++g)
#pragma unroll
    for (int dt = 0; dt < 4; ++dt) o[g][dt] = (f32x4){0.f, 0.f, 0.f, 0.f};

  const int nb = 2 * qt + 2;
  STAGE(0, 0);  // prologue: tile 0 in flight
  int cur = 0;

  for (int ib = 0; ib < nb; ++ib) {
    const int s0 = ib << 6;
    // compiler drains vmcnt+lgkmcnt before s_barrier -> buf[cur] visible
    __syncthreads();
    if (ib + 1 < nb) STAGE(cur ^ 1, s0 + 64);  // in flight across compute

    // ---- S^T = K Q^T, K-frags read once, shared across both q-tiles ----
    f32x4 st[2][4];
    __builtin_amdgcn_s_setprio(1);
#pragma unroll
    for (int kt = 0; kt < 4; ++kt) {
      const char* kb = (const char*)Ks[cur];
      short8 af0 = *(const short8*)(kb + swz_frag64(kt * 16 + c, quad, 0));
      short8 af1 = *(const short8*)(kb + swz_frag64(kt * 16 + c, quad, 1));
#pragma unroll
      for (int g = 0; g < 2; ++g) {
        f32x4 a = (f32x4){0.f, 0.f, 0.f, 0.f};
        a = __builtin_amdgcn_mfma_f32_16x16x32_bf16(af0, qf[g][0], a, 0, 0, 0);
        a = __builtin_amdgcn_mfma_f32_16x16x32_bf16(af1, qf[g][1], a, 0, 0, 0);
        st[g][kt] = a;
      }
    }
    __builtin_amdgcn_s_setprio(0);

#pragma unroll
    for (int g = 0; g < 2; ++g) {
      const int qbase = t0 + 32 * w + 16 * g;
      if (s0 + 63 > qbase) {  // causal mask for this (wave, g)
#pragma unroll
        for (int kt = 0; kt < 4; ++kt)
#pragma unroll
          for (int r = 0; r < 4; ++r)
            if (s0 + kt * 16 + 4 * quad + r > qbase + c) st[g][kt][r] = -1e30f;
      }
      float lacc = 0.f;
#pragma unroll
      for (int kt = 0; kt < 4; ++kt) {
        float p0 = fast_exp2(st[g][kt][0]);
        float p1 = fast_exp2(st[g][kt][1]);
        float p2 = fast_exp2(st[g][kt][2]);
        float p3 = fast_exp2(st[g][kt][3]);
        lacc += (p0 + p1) + (p2 + p3);
        uint2 pw = {cvt_pk_bf16(p0, p1), cvt_pk_bf16(p2, p3)};
        *(uint2*)(&Ps[w][g * 16 + c][kt * 16 + 4 * quad]) = pw;
      }
      l_i[g] += lacc;
    }

    // ---- O^T += V^T P^T (V-frags shared across both q-tiles) ----
    short8 pf[2][2];
#pragma unroll
    for (int g = 0; g < 2; ++g) {
      pf[g][0] = *(const short8*)(&Ps[w][g * 16 + c][quad * 8]);
      pf[g][1] = *(const short8*)(&Ps[w][g * 16 + c][32 + quad * 8]);
    }
    __builtin_amdgcn_s_setprio(1);
#pragma unroll
    for (int dt = 0; dt < 4; ++dt) {
      const char* vb = (const char*)Vs[cur];
      short8 vf0 = *(const short8*)(vb + swz_frag64(dt * 16 + c, quad, 0));
      short8 vf1 = *(const short8*)(vb + swz_frag64(dt * 16 + c, quad, 1));
#pragma unroll
      for (int g = 0; g < 2; ++g) {
        o[g][dt] =
            __builtin_amdgcn_mfma_f32_16x16x32_bf16(vf0, pf[g][0], o[g][dt], 0, 0, 0);
        o[g][dt] =
            __builtin_amdgcn_mfma_f32_16x16x32_bf16(vf1, pf[g][1], o[g][dt], 0, 0, 0);
      }
    }
    __builtin_amdgcn_s_setprio(0);
    cur ^= 1;
  }
#undef STAGE

  float linv[2];
#pragma unroll
  for (int g = 0; g < 2; ++g) {
    float ls = l_i[g];
    ls += __shfl_xor(ls, 16);
    ls += __shfl_xor(ls, 32);
    linv[g] = 1.0f / ls;
  }

  const int b = bh >> 4, h = bh & 15;
#pragma unroll
  for (int g = 0; g < 2; ++g) {
    const int row = t0 + 32 * w + 16 * g + c;
    ushort* dst = y2 + (size_t)(b * T_ + row) * C_ + h * 64;
#pragma unroll
    for (int dt = 0; dt < 4; ++dt) {
      uint2 ov = {cvt_pk_bf16(o[g][dt][0] * linv[g], o[g][dt][1] * linv[g]),
                  cvt_pk_bf16(o[g][dt][2] * linv[g], o[g][dt][3] * linv[g])};
      *(uint2*)(dst + dt * 16 + 4 * quad) = ov;
    }
  }
}

// ---------------------------------------------------------------------------
extern "C" void kernel_launch(void* const* d_in, const int* in_sizes, int n_in,
                              void* d_out, int out_size, void* d_ws,
                              size_t ws_size, hipStream_t stream) {
  const float* x = (const float*)d_in[0];
  const float* Wqkv = (const float*)d_in[1];
  const float* bqkv = (const float*)d_in[2];
  const float* Wproj = (const float*)d_in[3];
  const float* bproj = (const float*)d_in[4];
  float* out = (float*)d_out;

  const size_t per = (size_t)B_ * H_ * T_ * D_;  // 8388608
  ushort* q = (ushort*)d_ws;
  ushort* k = q + per;
  ushort* v = k + per;  // [B,H,D,T]
  ushort* y2 = v + per;
  ushort* xb = y2 + per;
  ushort* Wqkvt = xb + per;              // [3072][1024]
  ushort* Wprojt = Wqkvt + 3 * C_ * C_;  // [1024][1024]

  prepass<<<dim3(12288), 256, 0, stream>>>(x, Wqkv, Wproj, xb, Wqkvt, Wprojt);
  gemm_qkv_mfma<<<dim3(768), 512, 0, stream>>>(xb, Wqkvt, bqkv, q, k, v);
  attn<<<dim3(1024), 256, 0, stream>>>(q, k, v, y2);
  gemm_proj_mfma<<<dim3(256), 512, 0, stream>>>(y2, Wprojt, bproj, out);
}